// Round 3
// baseline (205.133 us; speedup 1.0000x reference)
//
#include <hip/hip_runtime.h>
#include <hip/hip_bf16.h>
#include <cstdint>

#define B_ 4
#define H_ 80
#define W_ 80
#define CH_ 256
#define NC_ 22
#define DIM_ 256
#define NPIX (B_*H_*W_)

typedef unsigned short ushort;
typedef __attribute__((ext_vector_type(8))) short short8;     // 8 bf16 = 4 VGPR
typedef __attribute__((ext_vector_type(4))) float floatx4;    // MFMA C/D frag

static __device__ inline ushort f2bf(float v) {
    __hip_bfloat16 h = __float2bfloat16(v);   // RNE
    ushort r;
    __builtin_memcpy(&r, &h, 2);
    return r;
}
static __device__ inline unsigned pk2(float a, float b) {
    return (unsigned)f2bf(a) | ((unsigned)f2bf(b) << 16);
}

// ---------------------------------------------------------------------------
// prep_w: weight repack only (sel moved into conv2).
// cw[c][k][d] f32 -> wbT[k][d][c] bf16 via LDS transpose. 72 blocks.
// ---------------------------------------------------------------------------
__global__ __launch_bounds__(256) void prep_w(const float* __restrict__ cw,
                                              ushort* __restrict__ wbT)
{
    __shared__ ushort ls[32][260];
    const int k  = blockIdx.x / 8;
    const int c0 = (blockIdx.x % 8) * 32;
    const int c    = threadIdx.x >> 3;                // 0..31
    const int seg8 = threadIdx.x & 7;                 // 0..7

    const float* src = cw + ((size_t)(c0 + c) * 9 + k) * DIM_ + seg8 * 32;
    #pragma unroll
    for (int e = 0; e < 32; e += 4) {
        float4 v = *(const float4*)(src + e);
        unsigned* dst = (unsigned*)&ls[c][seg8 * 32 + e];
        dst[0] = pk2(v.x, v.y);
        dst[1] = pk2(v.z, v.w);
    }
    __syncthreads();

    const int d = threadIdx.x;                        // 0..255
    ushort tmp[32];
    #pragma unroll
    for (int cc = 0; cc < 32; ++cc) tmp[cc] = ls[cc][d];
    uint4 o[4];
    __builtin_memcpy(o, tmp, 64);
    uint4* dst = (uint4*)(wbT + ((size_t)k * 256 + d) * 256 + c0);
    dst[0] = o[0]; dst[1] = o[1]; dst[2] = o[2]; dst[3] = o[3];
}

// ---------------------------------------------------------------------------
// conv2: taps-outer implicit GEMM, scale folded into bf16 staging.
// Waves 2wm x 2wn, jn=4 (each A ds_read_b128 feeds 4 MFMAs). M=80 padded to
// 96; phantom rows clamp onto rows 64..79 (their outputs are never stored).
// sel computed in-block (3-phase prologue) -> sl[9][80]; no ssel workspace.
// Per interval (ONE barrier, round-0 B discipline):
//   [bar] -> stage_load(it+1)   (10 global f32 loads, full-interval window)
//        -> kk0..kk3: {3 ds_read_b128 ; 12 MFMA}   (NO vmem consumed here)
//        -> loadBall(it+1)      (16 B loads, after last rg use)
//        -> stage_write(it+1)   (scale s*x in f32, pack bf16, ds_write)
//   [bar] (drains everything; B consumed only next interval)
// ---------------------------------------------------------------------------
__global__ __launch_bounds__(256, 2) void conv2(const float* __restrict__ x,
                                                const float* __restrict__ seg,
                                                const ushort* __restrict__ wbT,
                                                float* __restrict__ out)
{
    __shared__ ushort xsA[2][80 * 136];      // 43.5 KB
    __shared__ float  sl[9][80];             // 2.8 KB (sel*norm, f32)
    __shared__ float  mxl[80];               // per-pixel channel max

    const int tid  = threadIdx.x;
    const int lane = tid & 63;
    const int wv   = tid >> 6;
    const int wm   = wv >> 1;                // row half: 0 -> rows 0..47, 1 -> 48..95
    const int wn   = wv & 1;                 // d half: wn*64
    const int ln   = lane & 15;
    const int quad = lane >> 4;
    const int rt   = blockIdx.x;             // b*H + h
    const int b    = rt / H_;
    const int h    = rt % H_;
    const int d0   = blockIdx.y * 128;

    // per-thread B base offset (ushort units)
    const int Dbase = (d0 + wn * 64 + ln) * 256 + quad * 8;

    floatx4 O[3][4];
    #pragma unroll
    for (int im = 0; im < 3; ++im)
        #pragma unroll
        for (int jn = 0; jn < 4; ++jn)
            O[im][jn] = (floatx4){0.f, 0.f, 0.f, 0.f};

    short8 rg[4][4];                          // ALL B frags for current interval

    auto loadBall = [&](int itn) {
        const int ii  = itn / 6;
        const int rem = itn % 6;
        const int ccn = (rem / 3) * 128;
        const int jjn = rem % 3;
        const int kn  = 3 * ii + jjn;
        const ushort* bb = wbT + (size_t)kn * 65536 + Dbase + ccn;
        #pragma unroll
        for (int kk = 0; kk < 4; ++kk)
            #pragma unroll
            for (int jn = 0; jn < 4; ++jn)
                rg[kk][jn] = *(const short8*)(bb + kk * 32 + jn * 4096);
    };

    // ---- staging pipeline: loads into dedicated regs, pack+write later ----
    float4 fa[5], fb[5];
    bool   okr[5];

    auto stage_load = [&](int nit) {
        const int ii  = nit / 6;
        const int rem = nit % 6;
        const int ccn = (rem / 3) * 128;
        const int jjn = rem % 3;
        const int rr  = h + ii - 1;
        const bool rowok = (rr >= 0) && (rr < H_);
        const float* xrow = x + ((size_t)((b * H_ + (rowok ? rr : 0)) * W_)) * CH_ + ccn;
        #pragma unroll
        for (int r = 0; r < 5; ++r) {
            const int q  = tid + 256 * r;
            const int qm = q >> 4;
            const int qc = q & 15;
            const int col = qm + jjn - 1;
            const bool v = rowok && (col >= 0) && (col < W_);
            okr[r] = v;
            const float* f = xrow + (size_t)(v ? col : 0) * CH_ + qc * 8;
            fa[r] = *(const float4*)f;
            fb[r] = *(const float4*)(f + 4);
        }
    };
    auto stage_write = [&](int nit) {
        const int ii  = nit / 6;
        const int rem = nit % 6;
        const int jjn = rem % 3;
        const int kn  = 3 * ii + jjn;
        ushort* wr = xsA[nit & 1];
        #pragma unroll
        for (int r = 0; r < 5; ++r) {
            const int q  = tid + 256 * r;
            const int qm = q >> 4;
            const int qc = q & 15;
            uint4 o = make_uint4(0u, 0u, 0u, 0u);
            if (okr[r]) {
                const float s = sl[kn][qm];
                o = make_uint4(pk2(s * fa[r].x, s * fa[r].y), pk2(s * fa[r].z, s * fa[r].w),
                               pk2(s * fb[r].x, s * fb[r].y), pk2(s * fb[r].z, s * fb[r].w));
            }
            *(uint4*)&wr[qm * 136 + qc * 8] = o;
        }
    };

    // ================= prologue =================
    stage_load(0);                            // x loads fly during sel phases

    const float* segrow = seg + ((size_t)(b * H_ + h) * W_) * NC_;

    // phase A: per-pixel channel max of the CENTER pixel
    if (tid < 80) {
        const float2* c2 = (const float2*)(segrow + tid * NC_);
        float mx = -1e30f;
        #pragma unroll
        for (int c = 0; c < 11; ++c) { float2 v = c2[c]; mx = fmaxf(mx, fmaxf(v.x, v.y)); }
        mxl[tid] = mx;
    }
    __syncthreads();

    // phase B: raw sel. t = px*3 + i (input row i), 3 col-taps each.
    if (tid < 240) {
        const int px = tid / 3;
        const int ig = tid - px * 3;          // i = 0..2
        const int hh = h + ig - 1;
        float sv[3] = {0.f, 0.f, 0.f};
        if (hh >= 0 && hh < H_) {
            const float mx = mxl[px];
            const float2* cc2 = (const float2*)(segrow + px * NC_);
            float cv[22];
            #pragma unroll
            for (int c = 0; c < 11; ++c) { float2 v = cc2[c]; cv[2*c] = v.x; cv[2*c+1] = v.y; }
            const float* nrow = seg + ((size_t)(b * H_ + hh) * W_) * NC_;
            #pragma unroll
            for (int j = 0; j < 3; ++j) {
                const int ww = px + j - 1;
                if (ww >= 0 && ww < W_) {
                    const float2* n2 = (const float2*)(nrow + ww * NC_);
                    float s = 0.f;
                    #pragma unroll
                    for (int c = 0; c < 11; ++c) {
                        float2 v = n2[c];
                        s += (cv[2*c]   == mx) ? v.x : 0.f;
                        s += (cv[2*c+1] == mx) ? v.y : 0.f;
                    }
                    sv[j] = s;
                }
            }
        }
        #pragma unroll
        for (int j = 0; j < 3; ++j) sl[ig * 3 + j][px] = sv[j];
    }
    __syncthreads();

    // phase C: fold norm = 9/cnt into sl
    if (tid < 80) {
        int cnt = 0; float rv[9];
        #pragma unroll
        for (int k = 0; k < 9; ++k) { rv[k] = sl[k][tid]; cnt += (rv[k] != 0.f) ? 1 : 0; }
        const float norm = (cnt > 0) ? 9.f / (float)cnt : 0.f;
        #pragma unroll
        for (int k = 0; k < 9; ++k) sl[k][tid] = rv[k] * norm;
    }
    __syncthreads();                          // sl final

    stage_write(0);
    loadBall(0);
    __syncthreads();                          // buf0 ready, B drained

    // ================= main loop =================
    #pragma unroll 2
    for (int it = 0; it < 18; ++it) {
        const ushort* bp = xsA[it & 1];
        const ushort* aps[3];
        #pragma unroll
        for (int im = 0; im < 3; ++im) {
            int row = wm * 48 + im * 16 + ln;
            if (row >= 80) row -= 16;         // phantom rows alias 64..79 (not stored)
            aps[im] = bp + row * 136 + quad * 8;
        }

        if (it < 17) stage_load(it + 1);      // full-interval latency window

        #pragma unroll
        for (int kk = 0; kk < 4; ++kk) {
            short8 a[3];
            #pragma unroll
            for (int im = 0; im < 3; ++im) a[im] = *(const short8*)(aps[im] + kk * 32);
            #pragma unroll
            for (int im = 0; im < 3; ++im)
                #pragma unroll
                for (int jn = 0; jn < 4; ++jn)
                    O[im][jn] = __builtin_amdgcn_mfma_f32_16x16x32_bf16(
                        a[im], rg[kk][jn], O[im][jn], 0, 0, 0);
        }

        if (it < 17) {
            loadBall(it + 1);                 // after last rg use; consumed after bar
            stage_write(it + 1);              // pack + ds_write just before barrier
        }
        __syncthreads();
    }

    // epilogue: C/D layout col(d)=lane&15, row(m)=quad*4+reg; skip phantom rows
    #pragma unroll
    for (int im = 0; im < 3; ++im) {
        if (!(wm == 1 && im == 2)) {
            #pragma unroll
            for (int jn = 0; jn < 4; ++jn) {
                const int dd = d0 + wn * 64 + jn * 16 + ln;
                #pragma unroll
                for (int r = 0; r < 4; ++r) {
                    const int m = wm * 48 + im * 16 + quad * 4 + r;
                    out[((size_t)(rt * W_ + m)) * DIM_ + dd] = O[im][jn][r];
                }
            }
        }
    }
}

extern "C" void kernel_launch(void* const* d_in, const int* in_sizes, int n_in,
                              void* d_out, int out_size, void* d_ws, size_t ws_size,
                              hipStream_t stream)
{
    const float* x   = (const float*)d_in[0];   // (4,80,80,256) f32
    const float* seg = (const float*)d_in[1];   // (4,80,80,22)  f32
    const float* cw  = (const float*)d_in[2];   // (256,3,3,256) f32
    float* out = (float*)d_out;

    ushort* wbT = (ushort*)d_ws;                 // 1179648 B

    prep_w<<<dim3(72), dim3(256), 0, stream>>>(cw, wbT);
    conv2<<<dim3(B_ * H_, 2), dim3(256), 0, stream>>>(x, seg, wbT, out);
}

// Round 4
// 168.572 us; speedup vs baseline: 1.2169x; 1.2169x over previous
//
#include <hip/hip_runtime.h>
#include <hip/hip_bf16.h>
#include <cstdint>

#define B_ 4
#define H_ 80
#define W_ 80
#define CH_ 256
#define NC_ 22
#define DIM_ 256
#define NPIX (B_*H_*W_)

typedef unsigned short ushort;
typedef __attribute__((ext_vector_type(8))) short short8;     // 8 bf16 = 4 VGPR
typedef __attribute__((ext_vector_type(4))) float floatx4;    // MFMA C/D frag

static __device__ inline ushort f2bf(float v) {
    __hip_bfloat16 h = __float2bfloat16(v);   // RNE
    ushort r;
    __builtin_memcpy(&r, &h, 2);
    return r;
}
static __device__ inline unsigned pk2(float a, float b) {
    return (unsigned)f2bf(a) | ((unsigned)f2bf(b) << 16);
}

// ---------------------------------------------------------------------------
// prep_w: weight repack. cw[c][k][d] f32 -> wbT[k][d][c] bf16 (LDS transpose).
// ---------------------------------------------------------------------------
__global__ __launch_bounds__(256) void prep_w(const float* __restrict__ cw,
                                              ushort* __restrict__ wbT)
{
    __shared__ ushort ls[32][260];
    const int k  = blockIdx.x / 8;
    const int c0 = (blockIdx.x % 8) * 32;
    const int c    = threadIdx.x >> 3;                // 0..31
    const int seg8 = threadIdx.x & 7;                 // 0..7

    const float* src = cw + ((size_t)(c0 + c) * 9 + k) * DIM_ + seg8 * 32;
    #pragma unroll
    for (int e = 0; e < 32; e += 4) {
        float4 v = *(const float4*)(src + e);
        unsigned* dst = (unsigned*)&ls[c][seg8 * 32 + e];
        dst[0] = pk2(v.x, v.y);
        dst[1] = pk2(v.z, v.w);
    }
    __syncthreads();

    const int d = threadIdx.x;                        // 0..255
    ushort tmp[32];
    #pragma unroll
    for (int cc = 0; cc < 32; ++cc) tmp[cc] = ls[cc][d];
    uint4 o[4];
    __builtin_memcpy(o, tmp, 64);
    uint4* dst = (uint4*)(wbT + ((size_t)k * 256 + d) * 256 + c0);
    dst[0] = o[0]; dst[1] = o[1]; dst[2] = o[2]; dst[3] = o[3];
}

// ---------------------------------------------------------------------------
// cvt_x: x f32 -> xb bf16 (13 MB). 8 elems/thread.
// ---------------------------------------------------------------------------
__global__ __launch_bounds__(256) void cvt_x(const float* __restrict__ x,
                                             ushort* __restrict__ xb)
{
    size_t idx = ((size_t)blockIdx.x * 256 + threadIdx.x) * 8;
    const float4* s = (const float4*)(x + idx);
    float4 a = s[0], b = s[1];
    uint4 o = make_uint4(pk2(a.x, a.y), pk2(a.z, a.w), pk2(b.x, b.y), pk2(b.z, b.w));
    *(uint4*)(xb + idx) = o;
}

// ---------------------------------------------------------------------------
// conv2: taps-outer implicit GEMM — PROVEN round-0 structure (77.5 us).
// Block = row (M=80) x 128 d, 4 waves (each: full M, 32 d's). Per interval
// it in [0,18): i=it/6, cc=((it%6)/3)*128, j=it%3, tap k=3i+j.
// P (fresh) += A*B over 4 kk; then O += ssel_k[m] * P (f32 on C-frag).
// A: LDS double-buffered (rows padded to 136 ush). B: global->reg, loaded
// AFTER last use, consumed only after barrier. One barrier per interval.
// NEW vs round-0: sel computed in-block (3-phase prologue) -> sl[9][80].
// ---------------------------------------------------------------------------
template<bool XB16>
__global__ __launch_bounds__(256, 3) void conv2(const float* __restrict__ x,
                                                const ushort* __restrict__ xb,
                                                const float* __restrict__ seg,
                                                const ushort* __restrict__ wbT,
                                                float* __restrict__ out)
{
    __shared__ ushort xsA[2][80 * 136];      // 43.5 KB
    __shared__ float  sl[9][80];             // 2.8 KB (sel*norm, f32)
    __shared__ float  mxl[80];               // per-pixel channel max

    const int tid  = threadIdx.x;
    const int lane = tid & 63;
    const int wv   = tid >> 6;               // d-offset wv*32
    const int ln   = lane & 15;
    const int quad = lane >> 4;
    const int rt   = blockIdx.x;             // b*H + h
    const int b    = rt / H_;
    const int h    = rt % H_;
    const int d0   = blockIdx.y * 128;

    // per-thread staging chunk constants
    int qm[5], qc[5];
    #pragma unroll
    for (int r = 0; r < 5; ++r) {
        int q = tid + 256 * r;
        qm[r] = q >> 4;
        qc[r] = q & 15;
    }

    floatx4 O[5][2];
    #pragma unroll
    for (int i = 0; i < 5; ++i)
        #pragma unroll
        for (int jn = 0; jn < 2; ++jn)
            O[i][jn] = (floatx4){0.f, 0.f, 0.f, 0.f};

    // staging pipeline registers
    uint4  sg[5];                    // bf16 path
    float4 fa[5], fb[5];             // fp32 fallback path
    bool   ok[5];

    auto stage_load = [&](int nit) {
        const int i   = nit / 6;
        const int rem = nit % 6;
        const int cc  = (rem / 3) * 128;
        const int jj  = rem % 3;
        const int rr  = h + i - 1;
        const bool rowok = (rr >= 0) && (rr < H_);
        const int rsafe = rowok ? rr : h;
        #pragma unroll
        for (int r = 0; r < 5; ++r) {
            const int col = qm[r] + jj - 1;
            const bool v = rowok && (col >= 0) && (col < W_);
            ok[r] = v;
            const size_t gp = ((size_t)(b * H_ + rsafe) * W_ + (v ? col : 0));
            if (XB16) {
                sg[r] = *(const uint4*)(xb + gp * CH_ + cc + qc[r] * 8);
            } else {
                const float* f = x + gp * CH_ + cc + qc[r] * 8;
                fa[r] = *(const float4*)f;
                fb[r] = *(const float4*)(f + 4);
            }
        }
    };
    auto stage_write = [&](int nit) {
        ushort* bp = xsA[nit & 1];
        #pragma unroll
        for (int r = 0; r < 5; ++r) {
            uint4 v;
            if (XB16) {
                v = ok[r] ? sg[r] : make_uint4(0u, 0u, 0u, 0u);
            } else {
                v = ok[r] ? make_uint4(pk2(fa[r].x, fa[r].y), pk2(fa[r].z, fa[r].w),
                                       pk2(fb[r].x, fb[r].y), pk2(fb[r].z, fb[r].w))
                          : make_uint4(0u, 0u, 0u, 0u);
            }
            *(uint4*)&bp[qm[r] * 136 + qc[r] * 8] = v;
        }
    };

    short8 Breg[8];                  // [kk][jn] for current interval
    auto loadB = [&](int nit) {
        const int i   = nit / 6;
        const int rem = nit % 6;
        const int cc  = (rem / 3) * 128;
        const int jj  = rem % 3;
        const int k   = 3 * i + jj;
        #pragma unroll
        for (int kk = 0; kk < 4; ++kk)
            #pragma unroll
            for (int jn = 0; jn < 2; ++jn)
                Breg[kk * 2 + jn] = *(const short8*)(wbT
                    + ((size_t)k * 256 + d0 + wv * 32 + jn * 16 + ln) * 256
                    + cc + kk * 32 + quad * 8);
    };

    // ================= prologue: in-block sel + stage(0) =================
    stage_load(0);                            // x/xb loads fly during sel phases

    const float* segrow = seg + ((size_t)(b * H_ + h) * W_) * NC_;

    // phase A: per-pixel channel max of the CENTER pixel
    if (tid < 80) {
        const float2* c2 = (const float2*)(segrow + tid * NC_);
        float mx = -1e30f;
        #pragma unroll
        for (int c = 0; c < 11; ++c) { float2 v = c2[c]; mx = fmaxf(mx, fmaxf(v.x, v.y)); }
        mxl[tid] = mx;
    }
    __syncthreads();

    // phase B: raw sel. t = px*3 + i (input row i), 3 col-taps each.
    if (tid < 240) {
        const int px = tid / 3;
        const int ig = tid - px * 3;          // i = 0..2
        const int hh = h + ig - 1;
        float sv[3] = {0.f, 0.f, 0.f};
        if (hh >= 0 && hh < H_) {
            const float mx = mxl[px];
            const float2* cc2 = (const float2*)(segrow + px * NC_);
            float cv[22];
            #pragma unroll
            for (int c = 0; c < 11; ++c) { float2 v = cc2[c]; cv[2*c] = v.x; cv[2*c+1] = v.y; }
            const float* nrow = seg + ((size_t)(b * H_ + hh) * W_) * NC_;
            #pragma unroll
            for (int j = 0; j < 3; ++j) {
                const int ww = px + j - 1;
                if (ww >= 0 && ww < W_) {
                    const float2* n2 = (const float2*)(nrow + ww * NC_);
                    float s = 0.f;
                    #pragma unroll
                    for (int c = 0; c < 11; ++c) {
                        float2 v = n2[c];
                        s += (cv[2*c]   == mx) ? v.x : 0.f;
                        s += (cv[2*c+1] == mx) ? v.y : 0.f;
                    }
                    sv[j] = s;
                }
            }
        }
        #pragma unroll
        for (int j = 0; j < 3; ++j) sl[ig * 3 + j][px] = sv[j];
    }
    __syncthreads();

    // phase C: fold norm = 9/cnt into sl
    if (tid < 80) {
        int cnt = 0; float rv[9];
        #pragma unroll
        for (int k = 0; k < 9; ++k) { rv[k] = sl[k][tid]; cnt += (rv[k] != 0.f) ? 1 : 0; }
        const float norm = (cnt > 0) ? 9.f / (float)cnt : 0.f;
        #pragma unroll
        for (int k = 0; k < 9; ++k) sl[k][tid] = rv[k] * norm;
    }
    __syncthreads();                          // sl final

    stage_write(0);
    loadB(0);
    __syncthreads();                          // buf0 ready, B drained

    // ================= main loop (round-0 schedule, verbatim) =============
    #pragma unroll 2
    for (int it = 0; it < 18; ++it) {
        const int i   = it / 6;
        const int rem = it % 6;
        const int jj  = rem % 3;
        const int k   = 3 * i + jj;
        const ushort* bp = xsA[it & 1];

        if (it < 17) stage_load(it + 1);     // globals in flight during MFMA

        floatx4 P[5][2];
        #pragma unroll
        for (int im = 0; im < 5; ++im)
            #pragma unroll
            for (int jn = 0; jn < 2; ++jn)
                P[im][jn] = (floatx4){0.f, 0.f, 0.f, 0.f};

        #pragma unroll
        for (int kk = 0; kk < 4; ++kk) {
            short8 a[5];
            #pragma unroll
            for (int im = 0; im < 5; ++im)
                a[im] = *(const short8*)&bp[(im * 16 + ln) * 136 + kk * 32 + quad * 8];
            #pragma unroll
            for (int im = 0; im < 5; ++im)
                #pragma unroll
                for (int jn = 0; jn < 2; ++jn)
                    P[im][jn] = __builtin_amdgcn_mfma_f32_16x16x32_bf16(
                        a[im], Breg[kk * 2 + jn], P[im][jn], 0, 0, 0);
        }

        if (it < 17) stage_write(it + 1);    // vmcnt wait lands after MFMA
        if (it < 17) loadB(it + 1);          // B for next interval in flight

        // scale-accumulate: O += s_k[m] * P  (row m = im*16 + quad*4 + r)
        #pragma unroll
        for (int im = 0; im < 5; ++im) {
            const float4 sv = *(const float4*)&sl[k][im * 16 + quad * 4];
            #pragma unroll
            for (int jn = 0; jn < 2; ++jn) {
                O[im][jn][0] += sv.x * P[im][jn][0];
                O[im][jn][1] += sv.y * P[im][jn][1];
                O[im][jn][2] += sv.z * P[im][jn][2];
                O[im][jn][3] += sv.w * P[im][jn][3];
            }
        }
        __syncthreads();
    }

    // epilogue: C/D layout col(d)=lane&15, row(m)=quad*4+reg
    #pragma unroll
    for (int im = 0; im < 5; ++im) {
        #pragma unroll
        for (int jn = 0; jn < 2; ++jn) {
            const int dd = d0 + wv * 32 + jn * 16 + ln;
            #pragma unroll
            for (int r = 0; r < 4; ++r) {
                const int m = im * 16 + quad * 4 + r;
                out[((size_t)(rt * W_ + m)) * DIM_ + dd] = O[im][jn][r];
            }
        }
    }
}

extern "C" void kernel_launch(void* const* d_in, const int* in_sizes, int n_in,
                              void* d_out, int out_size, void* d_ws, size_t ws_size,
                              hipStream_t stream)
{
    const float* x   = (const float*)d_in[0];   // (4,80,80,256) f32
    const float* seg = (const float*)d_in[1];   // (4,80,80,22)  f32
    const float* cw  = (const float*)d_in[2];   // (256,3,3,256) f32
    float* out = (float*)d_out;

    ushort* wbT = (ushort*)d_ws;                               // 1179648 B
    ushort* xb  = (ushort*)((char*)d_ws + 1179648);            // 13107200 B
    const size_t need = 1179648u + 13107200u;

    prep_w<<<dim3(72), dim3(256), 0, stream>>>(cw, wbT);

    if (ws_size >= need) {
        cvt_x<<<dim3(NPIX * CH_ / (256 * 8)), dim3(256), 0, stream>>>(x, xb);
        conv2<true><<<dim3(B_ * H_, 2), dim3(256), 0, stream>>>(x, xb, seg, wbT, out);
    } else {
        conv2<false><<<dim3(B_ * H_, 2), dim3(256), 0, stream>>>(x, nullptr, seg, wbT, out);
    }
}